// Round 1
// baseline (128.650 us; speedup 1.0000x reference)
//
#include <hip/hip_runtime.h>

static constexpr int W56     = 56;
static constexpr int SPATIAL = 56 * 56;       // 3136
static constexpr int CH      = 64;
static constexpr int NCB     = 16;

// Block: 256 threads = 256 consecutive output points.
// blockIdx & 3  -> channel quarter (16 channels)
// blockIdx >> 2 -> point block (196 of them, 196*256 = 50176 exactly)
__global__ __launch_bounds__(256) void maddness_conv(
    const float* __restrict__ x,
    const int*   __restrict__ split_idxs,
    const float* __restrict__ split_vals,
    const float* __restrict__ lut,
    const float* __restrict__ bias,
    float*       __restrict__ out)
{
    __shared__ float4 lutq[NCB * 16 * 5];   // 20 KiB: quarter LUT rows, stride 5 float4 (pad breaks enc-bank aliasing)
    __shared__ float  svals[512];
    __shared__ int    selOff[64];
    __shared__ int    selDy[64];
    __shared__ int    selDx[64];
    __shared__ float4 biasq4[4];

    const int tid  = threadIdx.x;
    const int q    = blockIdx.x & 3;
    const int pblk = blockIdx.x >> 2;

    // ---- stage quarter LUT: 16 cb x 16 enc x 4 float4 = 1024 float4 ----
    const float4* lut4 = reinterpret_cast<const float4*>(lut);
    #pragma unroll
    for (int i = 0; i < 4; ++i) {
        int idx = tid + i * 256;            // 0..1023
        int row = idx >> 2;                 // cb*16 + enc
        int j   = idx & 3;
        lutq[row * 5 + j] = lut4[(row << 4) + (q << 2) + j];
    }
    // ---- thresholds ----
    svals[tid]       = split_vals[tid];
    svals[tid + 256] = split_vals[tid + 256];
    // ---- per-(cb,t) gather geometry: g = cb*36 + idx; ch=g/9; k=g%9; dy=k/3-1; dx=k%3-1 ----
    if (tid < 64) {
        int g  = (tid >> 2) * 36 + split_idxs[tid];
        int ch = g / 9;
        int k  = g - ch * 9;
        int ki = k / 3;
        int dy = ki - 1;
        int dx = (k - ki * 3) - 1;
        selOff[tid] = ch * SPATIAL + dy * W56 + dx;
        selDy[tid]  = dy;
        selDx[tid]  = dx;
    }
    if (tid < 4) biasq4[tid] = reinterpret_cast<const float4*>(bias)[(q << 2) + tid];
    __syncthreads();

    const int p  = pblk * 256 + tid;        // < 50176 exactly, no bounds check
    const int b  = p / SPATIAL;
    const int s  = p - b * SPATIAL;
    const int y  = s / W56;
    const int xc = s - y * W56;
    const float* __restrict__ xb = x + b * (CH * SPATIAL);

    float4 a0 = biasq4[0], a1 = biasq4[1], a2 = biasq4[2], a3 = biasq4[3];

    #pragma unroll
    for (int cb = 0; cb < NCB; ++cb) {
        int e = 0;
        #pragma unroll
        for (int t = 0; t < 4; ++t) {
            const int i  = cb * 4 + t;
            const int yy = y  + selDy[i];
            const int xx = xc + selDx[i];
            float v = 0.0f;
            if ((unsigned)yy < (unsigned)W56 && (unsigned)xx < (unsigned)W56)
                v = xb[selOff[i] + s];      // coalesced: consecutive lanes -> consecutive s
            e = (e << 1) | (v >= svals[i * 8 + e] ? 1 : 0);
        }
        const float4* row = &lutq[(cb * 16 + e) * 5];
        a0 += row[0];
        a1 += row[1];
        a2 += row[2];
        a3 += row[3];
    }

    float* __restrict__ op = out + b * (CH * SPATIAL) + (q * 16) * SPATIAL + s;
    op[ 0 * SPATIAL] = a0.x; op[ 1 * SPATIAL] = a0.y; op[ 2 * SPATIAL] = a0.z; op[ 3 * SPATIAL] = a0.w;
    op[ 4 * SPATIAL] = a1.x; op[ 5 * SPATIAL] = a1.y; op[ 6 * SPATIAL] = a1.z; op[ 7 * SPATIAL] = a1.w;
    op[ 8 * SPATIAL] = a2.x; op[ 9 * SPATIAL] = a2.y; op[10 * SPATIAL] = a2.z; op[11 * SPATIAL] = a2.w;
    op[12 * SPATIAL] = a3.x; op[13 * SPATIAL] = a3.y; op[14 * SPATIAL] = a3.z; op[15 * SPATIAL] = a3.w;
}

extern "C" void kernel_launch(void* const* d_in, const int* in_sizes, int n_in,
                              void* d_out, int out_size, void* d_ws, size_t ws_size,
                              hipStream_t stream) {
    const float* x  = (const float*)d_in[0];
    const int*   si = (const int*)  d_in[1];
    const float* sv = (const float*)d_in[2];
    const float* lt = (const float*)d_in[3];
    const float* bs = (const float*)d_in[4];
    float* o = (float*)d_out;

    // 196 point-blocks * 4 channel quarters
    maddness_conv<<<dim3(196 * 4), dim3(256), 0, stream>>>(x, si, sv, lt, bs, o);
}

// Round 2
// 80.436 us; speedup vs baseline: 1.5994x; 1.5994x over previous
//
#include <hip/hip_runtime.h>

static constexpr int W56     = 56;
static constexpr int SPATIAL = 56 * 56;       // 3136
static constexpr int CH      = 64;
static constexpr int NCB     = 16;

// Block: 256 threads = 256 consecutive output points.
// blockIdx & 3  -> channel quarter (16 channels)
// blockIdx >> 2 -> point block (196 of them, 196*256 = 50176 exactly)
__global__ __launch_bounds__(256) void maddness_conv(
    const float* __restrict__ x,
    const int*   __restrict__ split_idxs,
    const float* __restrict__ split_vals,
    const float* __restrict__ lut,
    const float* __restrict__ bias,
    float*       __restrict__ out)
{
    __shared__ float4 lutq[NCB * 16 * 5];   // 20 KiB: quarter LUT rows, stride 5 float4 (enc vs enc+8 alias only = free 2-way)
    __shared__ float  svals[512];
    __shared__ int    selChOff[64];         // ch*SPATIAL
    __shared__ int    selDy[64];
    __shared__ int    selDx[64];
    __shared__ float4 biasq4[4];

    const int tid  = threadIdx.x;
    const int q    = blockIdx.x & 3;
    const int pblk = blockIdx.x >> 2;

    // ---- stage quarter LUT: 16 cb x 16 enc x 4 float4 = 1024 float4 ----
    const float4* lut4 = reinterpret_cast<const float4*>(lut);
    #pragma unroll
    for (int i = 0; i < 4; ++i) {
        int idx = tid + i * 256;            // 0..1023
        int row = idx >> 2;                 // cb*16 + enc
        int j   = idx & 3;
        lutq[row * 5 + j] = lut4[(row << 4) + (q << 2) + j];
    }
    // ---- thresholds ----
    svals[tid]       = split_vals[tid];
    svals[tid + 256] = split_vals[tid + 256];
    // ---- per-(cb,t) gather geometry: g = cb*36 + idx; ch=g/9; k=g%9; dy=k/3-1; dx=k%3-1 ----
    if (tid < 64) {
        int g  = (tid >> 2) * 36 + split_idxs[tid];
        int ch = g / 9;
        int k  = g - ch * 9;
        int ki = k / 3;
        int dy = ki - 1;
        int dx = (k - ki * 3) - 1;
        selChOff[tid] = ch * SPATIAL;
        selDy[tid]    = dy;
        selDx[tid]    = dx;
    }
    if (tid < 4) biasq4[tid] = reinterpret_cast<const float4*>(bias)[(q << 2) + tid];
    __syncthreads();

    const int p  = pblk * 256 + tid;        // < 50176 exactly, no bounds check
    const int b  = p / SPATIAL;
    const int s  = p - b * SPATIAL;
    const int y  = s / W56;
    const int xc = s - y * W56;
    const float* __restrict__ xb = x + b * (CH * SPATIAL);

    // ---- branch-free gather of all 64 tree-node values (one straight-line BB
    //      so the compiler hoists every global_load and batches vmcnt) ----
    float v[NCB][4];
    #pragma unroll
    for (int cb = 0; cb < NCB; ++cb) {
        #pragma unroll
        for (int t = 0; t < 4; ++t) {
            const int i  = cb * 4 + t;
            const int yy = y  + selDy[i];
            const int xx = xc + selDx[i];
            const bool ok = ((unsigned)yy < (unsigned)W56) & ((unsigned)xx < (unsigned)W56);
            const int yyc = min(max(yy, 0), W56 - 1);      // clamp -> always-legal address
            const int xxc = min(max(xx, 0), W56 - 1);
            const float lv = xb[selChOff[i] + yyc * W56 + xxc];
            v[cb][t] = ok ? lv : 0.0f;                     // zero-pad semantics
        }
    }

    float4 a0 = biasq4[0], a1 = biasq4[1], a2 = biasq4[2], a3 = biasq4[3];

    #pragma unroll
    for (int cb = 0; cb < NCB; ++cb) {
        int e = 0;
        #pragma unroll
        for (int t = 0; t < 4; ++t) {
            e = (e << 1) | (v[cb][t] >= svals[(cb * 4 + t) * 8 + e] ? 1 : 0);
        }
        const float4* row = &lutq[(cb * 16 + e) * 5];
        a0 += row[0];
        a1 += row[1];
        a2 += row[2];
        a3 += row[3];
    }

    float* __restrict__ op = out + b * (CH * SPATIAL) + (q * 16) * SPATIAL + s;
    op[ 0 * SPATIAL] = a0.x; op[ 1 * SPATIAL] = a0.y; op[ 2 * SPATIAL] = a0.z; op[ 3 * SPATIAL] = a0.w;
    op[ 4 * SPATIAL] = a1.x; op[ 5 * SPATIAL] = a1.y; op[ 6 * SPATIAL] = a1.z; op[ 7 * SPATIAL] = a1.w;
    op[ 8 * SPATIAL] = a2.x; op[ 9 * SPATIAL] = a2.y; op[10 * SPATIAL] = a2.z; op[11 * SPATIAL] = a2.w;
    op[12 * SPATIAL] = a3.x; op[13 * SPATIAL] = a3.y; op[14 * SPATIAL] = a3.z; op[15 * SPATIAL] = a3.w;
}

extern "C" void kernel_launch(void* const* d_in, const int* in_sizes, int n_in,
                              void* d_out, int out_size, void* d_ws, size_t ws_size,
                              hipStream_t stream) {
    const float* x  = (const float*)d_in[0];
    const int*   si = (const int*)  d_in[1];
    const float* sv = (const float*)d_in[2];
    const float* lt = (const float*)d_in[3];
    const float* bs = (const float*)d_in[4];
    float* o = (float*)d_out;

    // 196 point-blocks * 4 channel quarters
    maddness_conv<<<dim3(196 * 4), dim3(256), 0, stream>>>(x, si, sv, lt, bs, o);
}

// Round 3
// 77.473 us; speedup vs baseline: 1.6606x; 1.0382x over previous
//
#include <hip/hip_runtime.h>
#include <hip/hip_fp16.h>

static constexpr int W56 = 56;
static constexpr int SP  = 56 * 56;   // 3136 = 49*64
static constexpr int CHN = 64;

__device__ __forceinline__ float rfl_f(float v) {
    return __int_as_float(__builtin_amdgcn_readfirstlane(__float_as_int(v)));
}

// grid = 784 blocks (16 b * 49 point-groups), block = 256 threads.
// Block covers 64 consecutive points (one batch image each) x all 64 channels.
// Phase 1: wave 'part' encodes codebooks [4*part, 4*part+4) for the 64 points.
// Phase 2: wave 'part' = channel quarter; per point sums 16 fp16 LUT rows.
__global__ __launch_bounds__(256, 3) void maddness_conv(
    const float* __restrict__ x,
    const int*   __restrict__ si,
    const float* __restrict__ sv,
    const float* __restrict__ lut,
    const float* __restrict__ bias,
    float*       __restrict__ out)
{
    __shared__ __half2        lutLds[256 * 36];  // row (cb*16+e): 32 half2 (64ch) + 4 pad -> 36.9 KB
    __shared__ unsigned short codes[256];        // [part*64 + lane]

    const int tid  = threadIdx.x;
    const int part = tid >> 6;                   // wave id = codebook group / quarter
    const int lane = tid & 63;

    const int b  = blockIdx.x / 49;              // scalar
    const int s  = (blockIdx.x - b * 49) * 64 + lane;
    const int y  = s / W56;
    const int xc = s - y * W56;
    const float* __restrict__ xb = x + b * (CHN * SP);

    // ---- phase 1a: issue all 16 gathers (branch-free, coalesced 256B/wave) ----
    float v[4][4];
    #pragma unroll
    for (int c = 0; c < 4; ++c) {
        #pragma unroll
        for (int t = 0; t < 4; ++t) {
            const int cb = part * 4 + c;
            const int i  = cb * 4 + t;
            const int g  = __builtin_amdgcn_readfirstlane(si[i]) + cb * 36; // wave-uniform
            const int ch = g / 9;
            const int k9 = g - ch * 9;
            const int ki = k9 / 3;
            const int dy = ki - 1;
            const int dx = (k9 - ki * 3) - 1;
            const int yy = y + dy, xx = xc + dx;
            const bool ok = ((unsigned)yy < (unsigned)W56) & ((unsigned)xx < (unsigned)W56);
            const int yyc = min(max(yy, 0), W56 - 1);
            const int xxc = min(max(xx, 0), W56 - 1);
            const float lv = xb[ch * SP + yyc * W56 + xxc];
            v[c][t] = ok ? lv : 0.0f;
        }
    }

    // ---- phase 1b: breadth-first threshold preload (independent, wave-uniform -> SGPRs) ----
    float T0[4], T1[4][2], T2[4][4], T3[4][8];
    #pragma unroll
    for (int c = 0; c < 4; ++c) {
        const int base = (part * 4 + c) * 32;
        T0[c] = rfl_f(sv[base]);
        #pragma unroll
        for (int j = 0; j < 2; ++j) T1[c][j] = rfl_f(sv[base + 8  + j]);
        #pragma unroll
        for (int j = 0; j < 4; ++j) T2[c][j] = rfl_f(sv[base + 16 + j]);
        #pragma unroll
        for (int j = 0; j < 8; ++j) T3[c][j] = rfl_f(sv[base + 24 + j]);
    }

    // ---- stage LUT fp32 -> fp16 pairs into LDS (overlaps gather/threshold latency) ----
    const float4* lut4 = reinterpret_cast<const float4*>(lut);
    #pragma unroll
    for (int i = 0; i < 16; ++i) {
        const int idx = tid + i * 256;           // 0..4095 float4s
        const int row = idx >> 4, k = idx & 15;
        const float4 f = lut4[idx];
        lutLds[row * 36 + 2 * k]     = __float22half2_rn(make_float2(f.x, f.y));
        lutLds[row * 36 + 2 * k + 1] = __float22half2_rn(make_float2(f.z, f.w));
    }

    // ---- phase 1c: pure-VALU select-tree encode (no memory in the chain) ----
    unsigned code = 0;
    #pragma unroll
    for (int c = 0; c < 4; ++c) {
        const bool b0 = v[c][0] >= T0[c];
        const float t1 = b0 ? T1[c][1] : T1[c][0];
        const bool b1 = v[c][1] >= t1;
        const float s01 = b1 ? T2[c][1] : T2[c][0];
        const float s23 = b1 ? T2[c][3] : T2[c][2];
        const bool b2 = v[c][2] >= (b0 ? s23 : s01);
        const float w0 = b2 ? T3[c][1] : T3[c][0];
        const float w1 = b2 ? T3[c][3] : T3[c][2];
        const float w2 = b2 ? T3[c][5] : T3[c][4];
        const float w3 = b2 ? T3[c][7] : T3[c][6];
        const float z0 = b1 ? w1 : w0;
        const float z1 = b1 ? w3 : w2;
        const bool b3 = v[c][3] >= (b0 ? z1 : z0);
        const int e = ((int)b0 << 3) | ((int)b1 << 2) | ((int)b2 << 1) | (int)b3;
        code |= (unsigned)e << (4 * c);
    }
    codes[part * 64 + lane] = (unsigned short)code;
    __syncthreads();

    // ---- phase 2: decode. wave 'part' = quarter q; 16 channels per thread ----
    const int q = part;
    const unsigned cd0 = codes[lane];
    const unsigned cd1 = codes[64 + lane];
    const unsigned cd2 = codes[128 + lane];
    const unsigned cd3 = codes[192 + lane];

    __half2 acc[8];
    #pragma unroll
    for (int r = 0; r < 8; ++r) acc[r] = __half2{__half(0.0f), __half(0.0f)};

    #pragma unroll
    for (int cb = 0; cb < 16; ++cb) {
        const unsigned cw = (cb < 4) ? cd0 : (cb < 8) ? cd1 : (cb < 12) ? cd2 : cd3;
        const int e = (int)((cw >> ((cb & 3) * 4)) & 15u);
        const __half2* __restrict__ row = &lutLds[(cb * 16 + e) * 36 + q * 8];
        #pragma unroll
        for (int r = 0; r < 8; ++r) acc[r] += row[r];   // v_pk_add_f16
    }

    float* __restrict__ op = out + b * (CHN * SP) + (q * 16) * SP + s;
    const float* __restrict__ bq = bias + q * 16;
    #pragma unroll
    for (int r = 0; r < 8; ++r) {
        const float2 f = __half22float2(acc[r]);
        op[(2 * r)     * SP] = f.x + bq[2 * r];
        op[(2 * r + 1) * SP] = f.y + bq[2 * r + 1];
    }
}

extern "C" void kernel_launch(void* const* d_in, const int* in_sizes, int n_in,
                              void* d_out, int out_size, void* d_ws, size_t ws_size,
                              hipStream_t stream) {
    const float* x  = (const float*)d_in[0];
    const int*   si = (const int*)  d_in[1];
    const float* sv = (const float*)d_in[2];
    const float* lt = (const float*)d_in[3];
    const float* bs = (const float*)d_in[4];
    float* o = (float*)d_out;

    maddness_conv<<<dim3(784), dim3(256), 0, stream>>>(x, si, sv, lt, bs, o);
}